// Round 1
// baseline (667.067 us; speedup 1.0000x reference)
//
#include <hip/hip_runtime.h>
#include <stdint.h>

#define EMB 2048
#define NH 16
#define QRANK 1536
#define KVRANK 512
#define ROPED 64
#define NOPED 64
#define VD 128
#define QKD 128
#define SEQ 2048
#define BATCH 2
#define BS 4096            // BATCH*SEQ
#define BHD 32             // BATCH*NH

typedef __attribute__((ext_vector_type(4))) float f32x4;
typedef __attribute__((ext_vector_type(8))) short s16x8;

__device__ __forceinline__ float bf2f(unsigned short u) {
  return __uint_as_float(((unsigned int)u) << 16);
}
__device__ __forceinline__ unsigned short f2bf(float f) {
  unsigned int u = __float_as_uint(f);
  u += 0x7fff + ((u >> 16) & 1);
  return (unsigned short)(u >> 16);
}

__device__ __forceinline__ void gld_lds16(const unsigned short* g, unsigned short* l) {
  __builtin_amdgcn_global_load_lds((const __attribute__((address_space(1))) void*)g,
                                   (__attribute__((address_space(3))) void*)l,
                                   16, 0, 0);
}

// ---------------- cast f32 -> bf16 (vectorized x4) ----------------
__global__ void cast_f32_bf16(const float* __restrict__ in, unsigned short* __restrict__ out, int n4) {
  int i = blockIdx.x * blockDim.x + threadIdx.x;
  int stride = gridDim.x * blockDim.x;
  for (; i < n4; i += stride) {
    float4 v = ((const float4*)in)[i];
    ushort4 o;
    o.x = f2bf(v.x); o.y = f2bf(v.y); o.z = f2bf(v.z); o.w = f2bf(v.w);
    ((ushort4*)out)[i] = o;
  }
}

// ---------------- GEMM: C[M,N] = A[M,K(lda)] * W[N,K(ldw)]^T ----------------
// bf16 inputs, fp32 accum, output bf16 (OUT_F32=0) or fp32 (OUT_F32=1).
// 128x128 tile, BK=64, 4 waves in 2x2, each wave 64x64 (4x4 MFMA tiles).
template <int OUT_F32>
__global__ __launch_bounds__(256, 2) void gemm_bt(
    const unsigned short* __restrict__ A, int lda,
    const unsigned short* __restrict__ W, int ldw,
    void* __restrict__ C, int M, int N, int K)
{
  __shared__ __align__(16) unsigned short As[128 * 64];
  __shared__ __align__(16) unsigned short Ws[128 * 64];
  const int tid = threadIdx.x;
  const int wave = tid >> 6;
  const int lane = tid & 63;
  const int ln = lane & 15;
  const int quad = lane >> 4;
  const int bm = blockIdx.y * 128;
  const int bn = blockIdx.x * 128;
  const int wm = (wave >> 1) * 64;
  const int wn = (wave & 1) * 64;

  f32x4 acc[4][4] = {};

  const int lrow8 = lane >> 3;      // 0..7
  const int lcol = (lane & 7) * 8;  // 0..56

  for (int k0 = 0; k0 < K; k0 += 64) {
#pragma unroll
    for (int it = 0; it < 4; ++it) {
      int rb = wave * 32 + it * 8;
      gld_lds16(A + (size_t)(bm + rb + lrow8) * lda + k0 + lcol, &As[rb * 64]);
    }
#pragma unroll
    for (int it = 0; it < 4; ++it) {
      int rb = wave * 32 + it * 8;
      int wr = bn + rb + lrow8;
      if (wr >= N) wr = N - 1;   // clamp (N=576 case); stores guarded below
      gld_lds16(W + (size_t)wr * ldw + k0 + lcol, &Ws[rb * 64]);
    }
    __syncthreads();
#pragma unroll
    for (int kk = 0; kk < 64; kk += 32) {
      s16x8 a[4], b[4];
#pragma unroll
      for (int mt = 0; mt < 4; ++mt)
        a[mt] = *(const s16x8*)&As[(wm + mt * 16 + ln) * 64 + kk + quad * 8];
#pragma unroll
      for (int nt = 0; nt < 4; ++nt)
        b[nt] = *(const s16x8*)&Ws[(wn + nt * 16 + ln) * 64 + kk + quad * 8];
#pragma unroll
      for (int mt = 0; mt < 4; ++mt)
#pragma unroll
        for (int nt = 0; nt < 4; ++nt)
          acc[mt][nt] = __builtin_amdgcn_mfma_f32_16x16x32_bf16(a[mt], b[nt], acc[mt][nt], 0, 0, 0);
    }
    __syncthreads();
  }
#pragma unroll
  for (int mt = 0; mt < 4; ++mt) {
    int row = bm + wm + mt * 16 + quad * 4;
#pragma unroll
    for (int nt = 0; nt < 4; ++nt) {
      int col = bn + wn + nt * 16 + ln;
      if (col < N) {
#pragma unroll
        for (int r = 0; r < 4; ++r) {
          float v = acc[mt][nt][r];
          if (OUT_F32)
            ((float*)C)[(size_t)(row + r) * N + col] = v;
          else
            ((unsigned short*)C)[(size_t)(row + r) * N + col] = f2bf(v);
        }
      }
    }
  }
}

// ---------------- prep Q: (4096, H*128) -> (B,H,S,128) with RoPE on dims 64..127 ----------------
__global__ void prep_q(const unsigned short* __restrict__ qm, unsigned short* __restrict__ Qry) {
  int bs = blockIdx.x;               // 0..4095
  int b = bs >> 11, s = bs & 2047;
  int tid = threadIdx.x;
  for (int idx = tid; idx < NH * 64; idx += 256) {   // 1024 pairs
    int h = idx >> 6, j = idx & 63;
    int d = 2 * j;
    float x0 = bf2f(qm[(size_t)bs * (NH * QKD) + h * QKD + d]);
    float x1 = bf2f(qm[(size_t)bs * (NH * QKD) + h * QKD + d + 1]);
    float y0 = x0, y1 = x1;
    if (j >= 32) {
      int i = j - 32;
      float theta = exp2f(-(float)i * (13.287712379549449f / 32.f)); // 10000^{-i/32}
      float ang = (float)s * theta;
      float sn, c;
      sincosf(ang, &sn, &c);
      y0 = x0 * c - x1 * sn;
      y1 = x1 * c + x0 * sn;
    }
    size_t o = ((size_t)(b * NH + h) * SEQ + s) * QKD + d;
    Qry[o] = f2bf(y0);
    Qry[o + 1] = f2bf(y1);
  }
}

// ---------------- prep K: kvb nope + RoPE(ckv rope part) -> (B,H,S,128) ----------------
__global__ void prep_key(const unsigned short* __restrict__ kvb,
                         const unsigned short* __restrict__ ckv,
                         unsigned short* __restrict__ Key) {
  __shared__ unsigned short krot[ROPED];
  int bs = blockIdx.x;
  int b = bs >> 11, s = bs & 2047;
  int tid = threadIdx.x;
  if (tid < 32) {
    int i = tid;
    float x0 = bf2f(ckv[(size_t)bs * (KVRANK + ROPED) + KVRANK + 2 * i]);
    float x1 = bf2f(ckv[(size_t)bs * (KVRANK + ROPED) + KVRANK + 2 * i + 1]);
    float theta = exp2f(-(float)i * (13.287712379549449f / 32.f));
    float ang = (float)s * theta;
    float sn, c;
    sincosf(ang, &sn, &c);
    krot[2 * i] = f2bf(x0 * c - x1 * sn);
    krot[2 * i + 1] = f2bf(x1 * c + x0 * sn);
  }
  __syncthreads();
  for (int idx = tid; idx < NH * QKD; idx += 256) {
    int h = idx >> 7, d = idx & 127;
    unsigned short v;
    if (d < NOPED)
      v = kvb[(size_t)bs * (NH * 192) + h * 192 + d];
    else
      v = krot[d - NOPED];
    Key[((size_t)(b * NH + h) * SEQ + s) * QKD + d] = v;
  }
}

// ---------------- transpose V: kvb[...,64:192] -> VT (B,H,128,S) ----------------
__global__ void transpose_v(const unsigned short* __restrict__ kvb, unsigned short* __restrict__ VT) {
  __shared__ unsigned short tile[64][132];  // pad to break conflicts
  int blk = blockIdx.x;        // bh*32 + st
  int bh = blk >> 5, st = blk & 31;
  int b = bh >> 4, h = bh & 15;
  int s0 = st * 64;
  int tid = threadIdx.x;
  for (int idx = tid; idx < 64 * 128; idx += 256) {
    int sl = idx >> 7, d = idx & 127;
    tile[sl][d] = kvb[((size_t)(b * SEQ + s0 + sl)) * (NH * 192) + h * 192 + NOPED + d];
  }
  __syncthreads();
  for (int idx = tid; idx < 64 * 128; idx += 256) {
    int d = idx >> 6, sl = idx & 63;
    VT[((size_t)bh * VD + d) * SEQ + s0 + sl] = tile[sl][d];
  }
}

// ---------------- flash attention: per (bh, 64-row q tile) ----------------
// Q,K: (BH, S, 128); VT: (BH, 128, S); O: (B, S, H*128) bf16
__global__ __launch_bounds__(256, 2) void flash_attn(
    const unsigned short* __restrict__ Q,
    const unsigned short* __restrict__ Kt,
    const unsigned short* __restrict__ VT,
    unsigned short* __restrict__ O)
{
  __shared__ __align__(16) unsigned short Qs[64 * 128];
  __shared__ __align__(16) unsigned short Ks[64 * 128];
  __shared__ __align__(16) unsigned short Vs[128 * 64];
  __shared__ __align__(16) unsigned short Ps[4][16 * 64];

  const int tid = threadIdx.x;
  const int wave = tid >> 6;
  const int lane = tid & 63;
  const int ln = lane & 15;
  const int quad = lane >> 4;
  const int bh = blockIdx.x;
  const int q0 = blockIdx.y * 64;

  // stage Q tile (64 x 128), stays resident
#pragma unroll
  for (int it = 0; it < 4; ++it) {
    int rb = wave * 16 + it * 4;
    gld_lds16(Q + ((size_t)bh * SEQ + q0 + rb + (lane >> 4)) * QKD + (lane & 15) * 8,
              &Qs[rb * 128]);
  }

  f32x4 o[8] = {};
  float m_i[4], l_i[4];
#pragma unroll
  for (int r = 0; r < 4; ++r) { m_i[r] = -1e30f; l_i[r] = 0.f; }

  for (int kt = 0; kt < SEQ / 64; ++kt) {
#pragma unroll
    for (int it = 0; it < 4; ++it) {
      int rb = wave * 16 + it * 4;
      gld_lds16(Kt + ((size_t)bh * SEQ + kt * 64 + rb + (lane >> 4)) * QKD + (lane & 15) * 8,
                &Ks[rb * 128]);
    }
#pragma unroll
    for (int it = 0; it < 4; ++it) {
      int rb = wave * 32 + it * 8;
      gld_lds16(VT + ((size_t)bh * VD + rb + (lane >> 3)) * SEQ + kt * 64 + (lane & 7) * 8,
                &Vs[rb * 64]);
    }
    __syncthreads();

    // S = Q K^T : wave's 16 q-rows x 64 keys
    f32x4 sc[4] = {};
#pragma unroll
    for (int kk = 0; kk < 128; kk += 32) {
      s16x8 aq = *(const s16x8*)&Qs[(wave * 16 + ln) * 128 + kk + quad * 8];
#pragma unroll
      for (int t = 0; t < 4; ++t) {
        s16x8 bk = *(const s16x8*)&Ks[(t * 16 + ln) * 128 + kk + quad * 8];
        sc[t] = __builtin_amdgcn_mfma_f32_16x16x32_bf16(aq, bk, sc[t], 0, 0, 0);
      }
    }

    // online softmax; rows handled by this lane: quad*4 + r
    float mx[4], al[4], rs[4];
#pragma unroll
    for (int r = 0; r < 4; ++r)
      mx[r] = fmaxf(fmaxf(sc[0][r], sc[1][r]), fmaxf(sc[2][r], sc[3][r]));
#pragma unroll
    for (int msk = 1; msk < 16; msk <<= 1)
#pragma unroll
      for (int r = 0; r < 4; ++r)
        mx[r] = fmaxf(mx[r], __shfl_xor(mx[r], msk));
#pragma unroll
    for (int r = 0; r < 4; ++r) {
      float mn = fmaxf(m_i[r], mx[r]);
      al[r] = __expf(m_i[r] - mn);
      m_i[r] = mn;
    }
    float p[4][4];
#pragma unroll
    for (int t = 0; t < 4; ++t)
#pragma unroll
      for (int r = 0; r < 4; ++r)
        p[t][r] = __expf(sc[t][r] - m_i[r]);
#pragma unroll
    for (int r = 0; r < 4; ++r)
      rs[r] = (p[0][r] + p[1][r]) + (p[2][r] + p[3][r]);
#pragma unroll
    for (int msk = 1; msk < 16; msk <<= 1)
#pragma unroll
      for (int r = 0; r < 4; ++r)
        rs[r] += __shfl_xor(rs[r], msk);
#pragma unroll
    for (int r = 0; r < 4; ++r)
      l_i[r] = l_i[r] * al[r] + rs[r];
#pragma unroll
    for (int t = 0; t < 8; ++t)
#pragma unroll
      for (int r = 0; r < 4; ++r)
        o[t][r] *= al[r];

    // P (C-layout) -> LDS (row-major 16x64, per-wave private) for A-operand reload
#pragma unroll
    for (int t = 0; t < 4; ++t)
#pragma unroll
      for (int r = 0; r < 4; ++r)
        Ps[wave][(quad * 4 + r) * 64 + t * 16 + ln] = f2bf(p[t][r]);
    asm volatile("s_waitcnt lgkmcnt(0)" ::: "memory");

    // O += P @ V
#pragma unroll
    for (int kk = 0; kk < 64; kk += 32) {
      s16x8 ap = *(const s16x8*)&Ps[wave][ln * 64 + kk + quad * 8];
#pragma unroll
      for (int t = 0; t < 8; ++t) {
        s16x8 bv = *(const s16x8*)&Vs[(t * 16 + ln) * 64 + kk + quad * 8];
        o[t] = __builtin_amdgcn_mfma_f32_16x16x32_bf16(ap, bv, o[t], 0, 0, 0);
      }
    }
    __syncthreads();
  }

  const int b = bh >> 4, h = bh & 15;
#pragma unroll
  for (int r = 0; r < 4; ++r) {
    float inv = 1.f / l_i[r];
    int s = q0 + wave * 16 + quad * 4 + r;
    size_t rowbase = ((size_t)b * SEQ + s) * (NH * VD) + h * VD;
#pragma unroll
    for (int t = 0; t < 8; ++t)
      O[rowbase + t * 16 + ln] = f2bf(o[t][r] * inv);
  }
}

static inline int imin_host(int a, int b) { return a < b ? a : b; }

extern "C" void kernel_launch(void* const* d_in, const int* in_sizes, int n_in,
                              void* d_out, int out_size, void* d_ws, size_t ws_size,
                              hipStream_t stream) {
  const float* x_f    = (const float*)d_in[0];
  const float* qaw_f  = (const float*)d_in[1];
  const float* qbw_f  = (const float*)d_in[2];
  const float* kvaw_f = (const float*)d_in[3];
  const float* kvbw_f = (const float*)d_in[4];
  const float* ow_f   = (const float*)d_in[5];

  char* ws = (char*)d_ws;
  size_t off = 0;
  auto alloc = [&](size_t n) {
    unsigned short* p = (unsigned short*)(ws + off);
    off = (off + n * 2 + 255) & ~(size_t)255;
    return p;
  };
  unsigned short* Xb   = alloc((size_t)BS * EMB);
  unsigned short* Wqa  = alloc((size_t)QRANK * EMB);
  unsigned short* Wqb  = alloc((size_t)(NH * QKD) * QRANK);
  unsigned short* Wkva = alloc((size_t)(KVRANK + ROPED) * EMB);
  unsigned short* Wkvb = alloc((size_t)(NH * 192) * KVRANK);
  unsigned short* Wo   = alloc((size_t)EMB * (NH * VD));
  unsigned short* CQ   = alloc((size_t)BS * QRANK);
  unsigned short* QM   = alloc((size_t)BS * (NH * QKD));
  unsigned short* CKV  = alloc((size_t)BS * (KVRANK + ROPED));
  unsigned short* KVB  = alloc((size_t)BS * (NH * 192));
  unsigned short* Qry  = alloc((size_t)BHD * SEQ * QKD);
  unsigned short* Key  = alloc((size_t)BHD * SEQ * QKD);
  unsigned short* Vt   = alloc((size_t)BHD * VD * SEQ);
  unsigned short* AO   = alloc((size_t)BS * (NH * VD));

  auto cast = [&](const float* src, unsigned short* dst, size_t n) {
    int n4 = (int)(n / 4);
    int blocks = imin_host((n4 + 255) / 256, 8192);
    cast_f32_bf16<<<dim3(blocks), 256, 0, stream>>>(src, dst, n4);
  };
  cast(x_f,    Xb,   (size_t)BS * EMB);
  cast(qaw_f,  Wqa,  (size_t)QRANK * EMB);
  cast(qbw_f,  Wqb,  (size_t)(NH * QKD) * QRANK);
  cast(kvaw_f, Wkva, (size_t)(KVRANK + ROPED) * EMB);
  cast(kvbw_f, Wkvb, (size_t)(NH * 192) * KVRANK);
  cast(ow_f,   Wo,   (size_t)EMB * (NH * VD));

  // cq = x @ q_a_w^T   (4096 x 1536, K=2048)
  gemm_bt<0><<<dim3(QRANK / 128, BS / 128), 256, 0, stream>>>(Xb, EMB, Wqa, EMB, CQ, BS, QRANK, EMB);
  // ckv = x @ kv_a_w^T (4096 x 576, K=2048)
  gemm_bt<0><<<dim3((KVRANK + ROPED + 127) / 128, BS / 128), 256, 0, stream>>>(Xb, EMB, Wkva, EMB, CKV, BS, KVRANK + ROPED, EMB);
  // q = cq @ q_b_w^T   (4096 x 2048, K=1536)
  gemm_bt<0><<<dim3((NH * QKD) / 128, BS / 128), 256, 0, stream>>>(CQ, QRANK, Wqb, QRANK, QM, BS, NH * QKD, QRANK);
  // kvb = ckv[:, :512] @ kv_b_w^T (4096 x 3072, K=512, lda=576)
  gemm_bt<0><<<dim3((NH * 192) / 128, BS / 128), 256, 0, stream>>>(CKV, KVRANK + ROPED, Wkvb, KVRANK, KVB, BS, NH * 192, KVRANK);

  prep_q<<<dim3(BS), 256, 0, stream>>>(QM, Qry);
  prep_key<<<dim3(BS), 256, 0, stream>>>(KVB, CKV, Key);
  transpose_v<<<dim3(BHD * (SEQ / 64)), 256, 0, stream>>>(KVB, Vt);

  flash_attn<<<dim3(BHD, SEQ / 64), 256, 0, stream>>>(Qry, Key, Vt, AO);

  // out = AO @ o_w^T (fp32 out)
  gemm_bt<1><<<dim3(EMB / 128, BS / 128), 256, 0, stream>>>(AO, NH * VD, Wo, NH * VD, d_out, BS, EMB, NH * VD);
}

// Round 2
// 470.276 us; speedup vs baseline: 1.4185x; 1.4185x over previous
//
#include <hip/hip_runtime.h>
#include <stdint.h>

#define EMB 2048
#define NH 16
#define QRANK 1536
#define KVRANK 512
#define ROPED 64
#define NOPED 64
#define VD 128
#define QKD 128
#define SEQ 2048
#define BATCH 2
#define BS 4096            // BATCH*SEQ
#define BHD 32             // BATCH*NH

typedef __attribute__((ext_vector_type(4))) float f32x4;
typedef __attribute__((ext_vector_type(8))) short s16x8;

__device__ __forceinline__ float bf2f(unsigned short u) {
  return __uint_as_float(((unsigned int)u) << 16);
}
__device__ __forceinline__ unsigned short f2bf(float f) {
  unsigned int u = __float_as_uint(f);
  u += 0x7fff + ((u >> 16) & 1);
  return (unsigned short)(u >> 16);
}

__device__ __forceinline__ void gld_lds16(const unsigned short* g, unsigned short* l) {
  __builtin_amdgcn_global_load_lds((const __attribute__((address_space(1))) void*)g,
                                   (__attribute__((address_space(3))) void*)l,
                                   16, 0, 0);
}

// ---------------- cast f32 -> bf16 (vectorized x4) ----------------
__global__ void cast_f32_bf16(const float* __restrict__ in, unsigned short* __restrict__ out, int n4) {
  int i = blockIdx.x * blockDim.x + threadIdx.x;
  int stride = gridDim.x * blockDim.x;
  for (; i < n4; i += stride) {
    float4 v = ((const float4*)in)[i];
    ushort4 o;
    o.x = f2bf(v.x); o.y = f2bf(v.y); o.z = f2bf(v.z); o.w = f2bf(v.w);
    ((ushort4*)out)[i] = o;
  }
}

// ---------------- GEMM: C[M,N] = A[M,K(lda)] * W[N,K(ldw)]^T ----------------
// 128x128 tile, BK=64, 4 waves 2x2, each wave 64x64. 16B-chunk XOR swizzle on
// LDS tiles (row stride 128B == exact bank wrap otherwise).
template <int OUT_F32>
__global__ __launch_bounds__(256, 2) void gemm_bt(
    const unsigned short* __restrict__ A, int lda,
    const unsigned short* __restrict__ W, int ldw,
    void* __restrict__ C, int M, int N, int K)
{
  __shared__ __align__(16) unsigned short As[128 * 64];
  __shared__ __align__(16) unsigned short Ws[128 * 64];
  const int tid = threadIdx.x;
  const int wave = tid >> 6;
  const int lane = tid & 63;
  const int ln = lane & 15;
  const int quad = lane >> 4;
  const int bm = blockIdx.y * 128;
  const int bn = blockIdx.x * 128;
  const int wm = (wave >> 1) * 64;
  const int wn = (wave & 1) * 64;

  f32x4 acc[4][4] = {};

  const int rel8 = lane >> 3;                    // relative row 0..7
  const int csw = ((lane & 7) ^ rel8) * 8;       // swizzled chunk offset (shorts)

  for (int k0 = 0; k0 < K; k0 += 64) {
#pragma unroll
    for (int it = 0; it < 4; ++it) {
      int rb = wave * 32 + it * 8;
      gld_lds16(A + (size_t)(bm + rb + rel8) * lda + k0 + csw, &As[rb * 64]);
    }
#pragma unroll
    for (int it = 0; it < 4; ++it) {
      int rb = wave * 32 + it * 8;
      int wr = bn + rb + rel8;
      if (wr >= N) wr = N - 1;   // clamp (N=576 case); stores guarded below
      gld_lds16(W + (size_t)wr * ldw + k0 + csw, &Ws[rb * 64]);
    }
    __syncthreads();
#pragma unroll
    for (int kk = 0; kk < 64; kk += 32) {
      s16x8 a[4], b[4];
#pragma unroll
      for (int mt = 0; mt < 4; ++mt)
        a[mt] = *(const s16x8*)&As[(wm + mt * 16 + ln) * 64 + ((kk / 8 + quad) ^ (ln & 7)) * 8];
#pragma unroll
      for (int nt = 0; nt < 4; ++nt)
        b[nt] = *(const s16x8*)&Ws[(wn + nt * 16 + ln) * 64 + ((kk / 8 + quad) ^ (ln & 7)) * 8];
#pragma unroll
      for (int mt = 0; mt < 4; ++mt)
#pragma unroll
        for (int nt = 0; nt < 4; ++nt)
          acc[mt][nt] = __builtin_amdgcn_mfma_f32_16x16x32_bf16(a[mt], b[nt], acc[mt][nt], 0, 0, 0);
    }
    __syncthreads();
  }
#pragma unroll
  for (int mt = 0; mt < 4; ++mt) {
    int row = bm + wm + mt * 16 + quad * 4;
#pragma unroll
    for (int nt = 0; nt < 4; ++nt) {
      int col = bn + wn + nt * 16 + ln;
      if (col < N) {
#pragma unroll
        for (int r = 0; r < 4; ++r) {
          float v = acc[mt][nt][r];
          if (OUT_F32)
            ((float*)C)[(size_t)(row + r) * N + col] = v;
          else
            ((unsigned short*)C)[(size_t)(row + r) * N + col] = f2bf(v);
        }
      }
    }
  }
}

// ---------------- prep Q: (4096, H*128) -> (B,H,S,128) with RoPE on dims 64..127 ----------------
__global__ void prep_q(const unsigned short* __restrict__ qm, unsigned short* __restrict__ Qry) {
  int bs = blockIdx.x;               // 0..4095
  int b = bs >> 11, s = bs & 2047;
  int tid = threadIdx.x;
  for (int idx = tid; idx < NH * 64; idx += 256) {   // 1024 pairs
    int h = idx >> 6, j = idx & 63;
    int d = 2 * j;
    float x0 = bf2f(qm[(size_t)bs * (NH * QKD) + h * QKD + d]);
    float x1 = bf2f(qm[(size_t)bs * (NH * QKD) + h * QKD + d + 1]);
    float y0 = x0, y1 = x1;
    if (j >= 32) {
      int i = j - 32;
      float theta = exp2f(-(float)i * (13.287712379549449f / 32.f)); // 10000^{-i/32}
      float ang = (float)s * theta;
      float sn, c;
      sincosf(ang, &sn, &c);
      y0 = x0 * c - x1 * sn;
      y1 = x1 * c + x0 * sn;
    }
    size_t o = ((size_t)(b * NH + h) * SEQ + s) * QKD + d;
    Qry[o] = f2bf(y0);
    Qry[o + 1] = f2bf(y1);
  }
}

// ---------------- prep K: kvb nope + RoPE(ckv rope part) -> (B,H,S,128) ----------------
__global__ void prep_key(const unsigned short* __restrict__ kvb,
                         const unsigned short* __restrict__ ckv,
                         unsigned short* __restrict__ Key) {
  __shared__ unsigned short krot[ROPED];
  int bs = blockIdx.x;
  int b = bs >> 11, s = bs & 2047;
  int tid = threadIdx.x;
  if (tid < 32) {
    int i = tid;
    float x0 = bf2f(ckv[(size_t)bs * (KVRANK + ROPED) + KVRANK + 2 * i]);
    float x1 = bf2f(ckv[(size_t)bs * (KVRANK + ROPED) + KVRANK + 2 * i + 1]);
    float theta = exp2f(-(float)i * (13.287712379549449f / 32.f));
    float ang = (float)s * theta;
    float sn, c;
    sincosf(ang, &sn, &c);
    krot[2 * i] = f2bf(x0 * c - x1 * sn);
    krot[2 * i + 1] = f2bf(x1 * c + x0 * sn);
  }
  __syncthreads();
  for (int idx = tid; idx < NH * QKD; idx += 256) {
    int h = idx >> 7, d = idx & 127;
    unsigned short v;
    if (d < NOPED)
      v = kvb[(size_t)bs * (NH * 192) + h * 192 + d];
    else
      v = krot[d - NOPED];
    Key[((size_t)(b * NH + h) * SEQ + s) * QKD + d] = v;
  }
}

// ---------------- transpose V: kvb[...,64:192] -> VT (B,H,128,S) ----------------
__global__ void transpose_v(const unsigned short* __restrict__ kvb, unsigned short* __restrict__ VT) {
  __shared__ unsigned short tile[64][132];  // pad to break conflicts
  int blk = blockIdx.x;        // bh*32 + st
  int bh = blk >> 5, st = blk & 31;
  int b = bh >> 4, h = bh & 15;
  int s0 = st * 64;
  int tid = threadIdx.x;
  for (int idx = tid; idx < 64 * 128; idx += 256) {
    int sl = idx >> 7, d = idx & 127;
    tile[sl][d] = kvb[((size_t)(b * SEQ + s0 + sl)) * (NH * 192) + h * 192 + NOPED + d];
  }
  __syncthreads();
  for (int idx = tid; idx < 64 * 128; idx += 256) {
    int d = idx >> 6, sl = idx & 63;
    VT[((size_t)bh * VD + d) * SEQ + s0 + sl] = tile[sl][d];
  }
}

// ---------------- flash attention v2: 128 q-rows/block, 32q x 64k per wave ----
// Q,K: (BH, S, 128); VT: (BH, 128, S); O: (B, S, H*128) bf16.
// All LDS tiles 16B-chunk XOR-swizzled (conflict-free b128). Q a-frags hoisted
// to registers; Q staging LDS is then reused as the per-wave P buffer.
__global__ __launch_bounds__(256, 2) void flash_attn(
    const unsigned short* __restrict__ Q,
    const unsigned short* __restrict__ Kt,
    const unsigned short* __restrict__ VT,
    unsigned short* __restrict__ O)
{
  __shared__ __align__(16) unsigned short QP[128 * 128];  // Q staging, then P (per-wave 32x64)
  __shared__ __align__(16) unsigned short Ks[64 * 128];
  __shared__ __align__(16) unsigned short Vs[128 * 64];

  const int tid = threadIdx.x;
  const int wave = tid >> 6;
  const int lane = tid & 63;
  const int ln = lane & 15;
  const int quad = lane >> 4;
  const int bh = blockIdx.x;
  const int q0 = blockIdx.y * 128;

  // ---- stage Q (128x128), 16-chunk swizzle: slot(R,c) holds global chunk c^(R&15)
  {
    int rel = lane >> 4, cch = lane & 15;
#pragma unroll
    for (int it = 0; it < 8; ++it) {
      int rb = wave * 32 + it * 4;
      int rr = rb + rel;
      int c = cch ^ (rr & 15);
      gld_lds16(Q + ((size_t)bh * SEQ + q0 + rr) * QKD + c * 8, &QP[rb * 128]);
    }
  }
  __syncthreads();

  // ---- hoist Q a-frags (rows wave*32+mt*16+ln, k-chunks kx*32)
  s16x8 qa[2][4];
#pragma unroll
  for (int mt = 0; mt < 2; ++mt) {
    int row = wave * 32 + mt * 16 + ln;
#pragma unroll
    for (int kx = 0; kx < 4; ++kx)
      qa[mt][kx] = *(const s16x8*)&QP[row * 128 + ((kx * 4 + quad) ^ ln) * 8];
  }
  // no barrier here: iter-0's post-stage barrier fences these reads before P writes

  unsigned short* Pw = &QP[wave * 2048];  // 32 rows x 64 cols, row-pair swizzled

  f32x4 o[2][8] = {};
  float m_i[2][4], l_i[2][4];
#pragma unroll
  for (int mt = 0; mt < 2; ++mt)
#pragma unroll
    for (int r = 0; r < 4; ++r) { m_i[mt][r] = -1e30f; l_i[mt][r] = 0.f; }

  const bool even = ((ln & 1) == 0);

  for (int kt = 0; kt < SEQ / 64; ++kt) {
    // stage K (64x128, 16-chunk swizzle) and V^T (128x64, 8-chunk swizzle)
    {
      int rel = lane >> 4, cch = lane & 15;
#pragma unroll
      for (int it = 0; it < 4; ++it) {
        int rb = wave * 16 + it * 4;
        int rr = rb + rel;
        int c = cch ^ (rr & 15);
        gld_lds16(Kt + ((size_t)bh * SEQ + kt * 64 + rr) * QKD + c * 8, &Ks[rb * 128]);
      }
      int rel8 = lane >> 3;
      int c8 = (lane & 7) ^ rel8;
#pragma unroll
      for (int it = 0; it < 4; ++it) {
        int rb = wave * 32 + it * 8;
        gld_lds16(VT + ((size_t)bh * VD + rb + rel8) * SEQ + kt * 64 + c8 * 8, &Vs[rb * 64]);
      }
    }
    __syncthreads();

    // ---- S = Q K^T (32q x 64k per wave)
    f32x4 sc[2][4] = {};
#pragma unroll
    for (int kx = 0; kx < 4; ++kx) {
      s16x8 bk[4];
#pragma unroll
      for (int t = 0; t < 4; ++t)
        bk[t] = *(const s16x8*)&Ks[(t * 16 + ln) * 128 + ((kx * 4 + quad) ^ ln) * 8];
#pragma unroll
      for (int mt = 0; mt < 2; ++mt)
#pragma unroll
        for (int t = 0; t < 4; ++t)
          sc[mt][t] = __builtin_amdgcn_mfma_f32_16x16x32_bf16(qa[mt][kx], bk[t], sc[mt][t], 0, 0, 0);
    }

    // ---- online softmax per (mt, r); row = mt*16 + quad*4 + r
    float al[2][4];
#pragma unroll
    for (int mt = 0; mt < 2; ++mt) {
      float mx[4], rs[4];
#pragma unroll
      for (int r = 0; r < 4; ++r)
        mx[r] = fmaxf(fmaxf(sc[mt][0][r], sc[mt][1][r]), fmaxf(sc[mt][2][r], sc[mt][3][r]));
#pragma unroll
      for (int msk = 1; msk < 16; msk <<= 1)
#pragma unroll
        for (int r = 0; r < 4; ++r)
          mx[r] = fmaxf(mx[r], __shfl_xor(mx[r], msk));
#pragma unroll
      for (int r = 0; r < 4; ++r) {
        float mn = fmaxf(m_i[mt][r], mx[r]);
        al[mt][r] = __expf(m_i[mt][r] - mn);
        m_i[mt][r] = mn;
        rs[r] = 0.f;
      }
#pragma unroll
      for (int t = 0; t < 4; ++t)
#pragma unroll
        for (int r = 0; r < 4; ++r) {
          float e = __expf(sc[mt][t][r] - m_i[mt][r]);
          sc[mt][t][r] = e;
          rs[r] += e;
        }
#pragma unroll
      for (int msk = 1; msk < 16; msk <<= 1)
#pragma unroll
        for (int r = 0; r < 4; ++r)
          rs[r] += __shfl_xor(rs[r], msk);
#pragma unroll
      for (int r = 0; r < 4; ++r)
        l_i[mt][r] = l_i[mt][r] * al[mt][r] + rs[r];
#pragma unroll
      for (int dt = 0; dt < 8; ++dt)
#pragma unroll
        for (int r = 0; r < 4; ++r)
          o[mt][dt][r] *= al[mt][r];
    }

    // ---- P -> LDS: pair columns via DPP shfl_xor(1), truncate to bf16, dword
    // writes by even lanes; chunk swizzled by (row>>1)&7 (row pairs share swizzle)
#pragma unroll
    for (int mt = 0; mt < 2; ++mt)
#pragma unroll
      for (int t = 0; t < 4; ++t) {
        unsigned int pu[4], nu[4];
#pragma unroll
        for (int r = 0; r < 4; ++r) {
          pu[r] = __float_as_uint(sc[mt][t][r]);
          nu[r] = __float_as_uint(__shfl_xor(sc[mt][t][r], 1));
        }
        if (even) {
          int cb = t * 2 + (ln >> 3);
          int rbase = mt * 16 + quad * 4;
#pragma unroll
          for (int rp = 0; rp < 2; ++rp) {
            int swc = cb ^ (quad * 2 + rp);
            unsigned short* a = &Pw[(rbase + 2 * rp) * 64 + swc * 8 + (ln & 7)];
            *(unsigned int*)a        = (pu[2 * rp] >> 16)     | (nu[2 * rp] & 0xffff0000u);
            *(unsigned int*)(a + 64) = (pu[2 * rp + 1] >> 16) | (nu[2 * rp + 1] & 0xffff0000u);
          }
        }
      }
    asm volatile("s_waitcnt lgkmcnt(0)" ::: "memory");

    // ---- O += P @ V
#pragma unroll
    for (int kc = 0; kc < 2; ++kc) {
      s16x8 ap[2];
#pragma unroll
      for (int mt = 0; mt < 2; ++mt)
        ap[mt] = *(const s16x8*)&Pw[(mt * 16 + ln) * 64 + ((kc * 4 + quad) ^ (ln >> 1)) * 8];
#pragma unroll
      for (int dt = 0; dt < 8; ++dt) {
        s16x8 bv = *(const s16x8*)&Vs[(dt * 16 + ln) * 64 + ((kc * 4 + quad) ^ (ln & 7)) * 8];
#pragma unroll
        for (int mt = 0; mt < 2; ++mt)
          o[mt][dt] = __builtin_amdgcn_mfma_f32_16x16x32_bf16(ap[mt], bv, o[mt][dt], 0, 0, 0);
      }
    }
    __syncthreads();
  }

  const int b = bh >> 4, h = bh & 15;
#pragma unroll
  for (int mt = 0; mt < 2; ++mt)
#pragma unroll
    for (int r = 0; r < 4; ++r) {
      float inv = 1.f / l_i[mt][r];
      int s = q0 + wave * 32 + mt * 16 + quad * 4 + r;
      size_t rowbase = ((size_t)b * SEQ + s) * (NH * VD) + h * VD;
#pragma unroll
      for (int dt = 0; dt < 8; ++dt)
        O[rowbase + dt * 16 + ln] = f2bf(o[mt][dt][r] * inv);
    }
}

static inline int imin_host(int a, int b) { return a < b ? a : b; }

extern "C" void kernel_launch(void* const* d_in, const int* in_sizes, int n_in,
                              void* d_out, int out_size, void* d_ws, size_t ws_size,
                              hipStream_t stream) {
  const float* x_f    = (const float*)d_in[0];
  const float* qaw_f  = (const float*)d_in[1];
  const float* qbw_f  = (const float*)d_in[2];
  const float* kvaw_f = (const float*)d_in[3];
  const float* kvbw_f = (const float*)d_in[4];
  const float* ow_f   = (const float*)d_in[5];

  char* ws = (char*)d_ws;
  size_t off = 0;
  auto alloc = [&](size_t n) {
    unsigned short* p = (unsigned short*)(ws + off);
    off = (off + n * 2 + 255) & ~(size_t)255;
    return p;
  };
  unsigned short* Xb   = alloc((size_t)BS * EMB);
  unsigned short* Wqa  = alloc((size_t)QRANK * EMB);
  unsigned short* Wqb  = alloc((size_t)(NH * QKD) * QRANK);
  unsigned short* Wkva = alloc((size_t)(KVRANK + ROPED) * EMB);
  unsigned short* Wkvb = alloc((size_t)(NH * 192) * KVRANK);
  unsigned short* Wo   = alloc((size_t)EMB * (NH * VD));
  unsigned short* CQ   = alloc((size_t)BS * QRANK);
  unsigned short* QM   = alloc((size_t)BS * (NH * QKD));
  unsigned short* CKV  = alloc((size_t)BS * (KVRANK + ROPED));
  unsigned short* KVB  = alloc((size_t)BS * (NH * 192));
  unsigned short* Qry  = alloc((size_t)BHD * SEQ * QKD);
  unsigned short* Key  = alloc((size_t)BHD * SEQ * QKD);
  unsigned short* Vt   = alloc((size_t)BHD * VD * SEQ);
  unsigned short* AO   = alloc((size_t)BS * (NH * VD));

  auto cast = [&](const float* src, unsigned short* dst, size_t n) {
    int n4 = (int)(n / 4);
    int blocks = imin_host((n4 + 255) / 256, 8192);
    cast_f32_bf16<<<dim3(blocks), 256, 0, stream>>>(src, dst, n4);
  };
  cast(x_f,    Xb,   (size_t)BS * EMB);
  cast(qaw_f,  Wqa,  (size_t)QRANK * EMB);
  cast(qbw_f,  Wqb,  (size_t)(NH * QKD) * QRANK);
  cast(kvaw_f, Wkva, (size_t)(KVRANK + ROPED) * EMB);
  cast(kvbw_f, Wkvb, (size_t)(NH * 192) * KVRANK);
  cast(ow_f,   Wo,   (size_t)EMB * (NH * VD));

  // cq = x @ q_a_w^T   (4096 x 1536, K=2048)
  gemm_bt<0><<<dim3(QRANK / 128, BS / 128), 256, 0, stream>>>(Xb, EMB, Wqa, EMB, CQ, BS, QRANK, EMB);
  // ckv = x @ kv_a_w^T (4096 x 576, K=2048)
  gemm_bt<0><<<dim3((KVRANK + ROPED + 127) / 128, BS / 128), 256, 0, stream>>>(Xb, EMB, Wkva, EMB, CKV, BS, KVRANK + ROPED, EMB);
  // q = cq @ q_b_w^T   (4096 x 2048, K=1536)
  gemm_bt<0><<<dim3((NH * QKD) / 128, BS / 128), 256, 0, stream>>>(CQ, QRANK, Wqb, QRANK, QM, BS, NH * QKD, QRANK);
  // kvb = ckv[:, :512] @ kv_b_w^T (4096 x 3072, K=512, lda=576)
  gemm_bt<0><<<dim3((NH * 192) / 128, BS / 128), 256, 0, stream>>>(CKV, KVRANK + ROPED, Wkvb, KVRANK, KVB, BS, NH * 192, KVRANK);

  prep_q<<<dim3(BS), 256, 0, stream>>>(QM, Qry);
  prep_key<<<dim3(BS), 256, 0, stream>>>(KVB, CKV, Key);
  transpose_v<<<dim3(BHD * (SEQ / 64)), 256, 0, stream>>>(KVB, Vt);

  flash_attn<<<dim3(BHD, SEQ / 128), 256, 0, stream>>>(Qry, Key, Vt, AO);

  // out = AO @ o_w^T (fp32 out)
  gemm_bt<1><<<dim3(EMB / 128, BS / 128), 256, 0, stream>>>(AO, NH * VD, Wo, NH * VD, d_out, BS, EMB, NH * VD);
}